// Round 9
// baseline (227.822 us; speedup 1.0000x reference)
//
#include <hip/hip_runtime.h>

#define BATCH 4
#define HH 1024
#define WW 1024

// ------- fused downsample(1024->256) + conv0 (3->8,s2) + conv1 (8->16,s2) ----
// 1024 blocks (4/CU). Each block: 4x4 x1-tile.
__global__ __launch_bounds__(256) void ds01_k(const float* __restrict__ img,
                                              const float* __restrict__ w0,
                                              const float* __restrict__ b0,
                                              const float* __restrict__ w1,
                                              const float* __restrict__ b1,
                                              float* __restrict__ out) {
  int blk = blockIdx.x;            // b*256 + ty*16 + tx
  int tx = blk & 15;
  int ty = (blk >> 4) & 15;
  int b = blk >> 8;
  int t = threadIdx.x;

  __shared__ float low[3][19][21];   // 4.8 KB
  __shared__ float x0s[8][9][12];    // 3.5 KB

  int Y0 = ty << 2, X0 = tx << 2;           // x1 tile origin (64x64 space)
  int gy0 = 2 * Y0 - 1, gx0 = 2 * X0 - 1;   // x0 support origin (9x9)
  int ly0 = 2 * gy0 - 1, lx0 = 2 * gx0 - 1; // low support origin (19x19)

  for (int i = t; i < 3 * 19 * 19; i += 256) {
    int c = i / 361;
    int rem = i - c * 361;
    int ly = rem / 19;
    int lx = rem - ly * 19;
    int gy = ly0 + ly, gx = lx0 + lx;        // in [-3, 255]
    float v = 0.f;
    if (gy >= 0 && gx >= 0) {
      const float* p = img + (size_t)(b * 3 + c) * HH * WW + (4 * gy + 1) * WW + 4 * gx;
      float4 u0 = *(const float4*)p;
      float4 u1 = *(const float4*)(p + WW);
      v = 0.25f * (u0.y + u0.z + u1.y + u1.z);
    }
    low[c][ly][lx] = v;
  }
  __syncthreads();

  for (int i = t; i < 8 * 81; i += 256) {
    int ch = i / 81;
    int pos = i - ch * 81;
    int py = pos / 9, px = pos - py * 9;
    int gy = gy0 + py, gx = gx0 + px;
    float v = 0.f;
    if (gy >= 0 && gx >= 0) {
      float a = b0[ch];
#pragma unroll
      for (int ci = 0; ci < 3; ++ci)
#pragma unroll
        for (int ky = 0; ky < 3; ++ky)
#pragma unroll
          for (int kx = 0; kx < 3; ++kx)
            a += low[ci][2 * py + ky][2 * px + kx] *
                 w0[ch * 27 + ci * 9 + ky * 3 + kx];
      v = fmaxf(a, 0.f);
    }
    x0s[ch][py][px] = v;
  }
  __syncthreads();

  {
    int oc = t >> 4;
    int pos = t & 15;
    int y = pos >> 2, x = pos & 3;
    float a = b1[oc];
#pragma unroll
    for (int ci = 0; ci < 8; ++ci)
#pragma unroll
      for (int ky = 0; ky < 3; ++ky)
#pragma unroll
        for (int kx = 0; kx < 3; ++kx)
          a += x0s[ci][2 * y + ky][2 * x + kx] *
               w1[(oc * 8 + ci) * 9 + ky * 3 + kx];
    out[(size_t)(b * 16 + oc) * 64 * 64 + (Y0 + y) * 64 + X0 + x] =
        fmaxf(a, 0.f);
  }
}

// ---- fused conv2 (16->32,s2) + conv3 (32->64,s2) via redundant halo ---------
// 256 blocks. Each block: 2x2 x3-tile. NO grid barrier (R7 lesson: spin
// barriers cost ~60us each on 8-XCD L2s).
__global__ __launch_bounds__(256) void conv23_k(const float* __restrict__ x1,
                                                const float* __restrict__ w2,
                                                const float* __restrict__ b2,
                                                const float* __restrict__ w3,
                                                const float* __restrict__ b3,
                                                float* __restrict__ x3) {
  int blk = blockIdx.x;            // b*64 + ty*8 + tx
  int tx = blk & 7;
  int ty = (blk >> 3) & 7;
  int b = blk >> 6;
  int t = threadIdx.x;

  __shared__ float x1h[16][11][12];  // 8.4 KB
  __shared__ float s2h[32][5][8];    // 5 KB

  int Y0 = ty << 1, X0 = tx << 1;           // x3 tile origin (16x16 space)
  int gy0 = 2 * Y0 - 1, gx0 = 2 * X0 - 1;   // x2 halo origin (5x5, 32-space)
  int r0 = 2 * gy0 - 1, c0 = 2 * gx0 - 1;   // x1 halo origin (11x11, 64-space)

  for (int i = t; i < 16 * 121; i += 256) {
    int c = i / 121;
    int rem = i - c * 121;
    int ly = rem / 11;
    int lx = rem - ly * 11;
    int gy = r0 + ly, gx = c0 + lx;
    float v = 0.f;
    if (gy >= 0 && gy < 64 && gx >= 0 && gx < 64)
      v = x1[((size_t)(b * 16 + c) * 64 + gy) * 64 + gx];
    x1h[c][ly][lx] = v;
  }
  __syncthreads();

  for (int i = t; i < 800; i += 256) {
    int ch = i / 25;
    int rem = i - ch * 25;
    int py = rem / 5, px = rem - py * 5;
    int gy = gy0 + py, gx = gx0 + px;
    float v = 0.f;
    if (gy >= 0 && gy < 32 && gx >= 0 && gx < 32) {
      float a = b2[ch];
      for (int ci = 0; ci < 16; ++ci) {
#pragma unroll
        for (int ky = 0; ky < 3; ++ky)
#pragma unroll
          for (int kx = 0; kx < 3; ++kx)
            a += x1h[ci][2 * py + ky][2 * px + kx] *
                 w2[(ch * 16 + ci) * 9 + ky * 3 + kx];
      }
      v = fmaxf(a, 0.f);
    }
    s2h[ch][py][px] = v;
  }
  __syncthreads();

  {
    int oc = t >> 2;
    int pos = t & 3;
    int y = pos >> 1, x = pos & 1;
    float a = b3[oc];
    for (int ci = 0; ci < 32; ++ci) {
#pragma unroll
      for (int ky = 0; ky < 3; ++ky)
#pragma unroll
        for (int kx = 0; kx < 3; ++kx)
          a += s2h[ci][2 * y + ky][2 * x + kx] *
               w3[(oc * 32 + ci) * 9 + ky * 3 + kx];
    }
    x3[(size_t)(b * 64 + oc) * 256 + (Y0 + y) * 16 + X0 + x] = fmaxf(a, 0.f);
  }
}

// ---------------- fused pointwise chain, 2 positions/block (512 blocks) ------
// CO=128 phases now CI FMA/thread (halved); 2 blocks/CU.
__global__ __launch_bounds__(256) void mlp_k(
    const float* __restrict__ x3, const float* __restrict__ spw,
    const float* __restrict__ spb, const float* __restrict__ val,
    const float* __restrict__ lw1, const float* __restrict__ lb1,
    const float* __restrict__ lw2, const float* __restrict__ lb2,
    const float* __restrict__ lw3, const float* __restrict__ lb3,
    const float* __restrict__ cw, const float* __restrict__ cb,
    const float* __restrict__ fw1, const float* __restrict__ fb1,
    const float* __restrict__ fw2, const float* __restrict__ fb2,
    const float* __restrict__ gw, const float* __restrict__ gb,
    float* __restrict__ gridt) {
  int blk = blockIdx.x;  // b*128 + g
  int b = blk >> 7;
  int p0 = (blk & 127) << 1;
  int t = threadIdx.x;

  __shared__ float A[128][2];
  __shared__ float Bf[128][2];
  __shared__ float effs[4][64];
  __shared__ float ebv[4];
  __shared__ float s8v[4][64];
  __shared__ float scv[64], h1v[64], f2v[64];

  if (t < 128)
    A[t >> 1][t & 1] = x3[((size_t)(b * 64 + (t >> 1))) * 256 + p0 + (t & 1)];
  {  // eff[ch][k] = sum_o cw[ch][o]*spw[o][k]
    int ch = t >> 6, k = t & 63;
    float a = 0.f;
#pragma unroll 8
    for (int o = 0; o < 64; ++o) a += cw[ch * 64 + o] * spw[o * 64 + k];
    effs[ch][k] = a;
    if (k == 0) {
      float a2 = 0.f;
      float vb = val[b];
#pragma unroll 8
      for (int o = 0; o < 64; ++o) a2 += cw[ch * 64 + o] * (spb[o] + vb);
      ebv[ch] = cb[ch] + a2;
    }
  }
  __syncthreads();
  {  // s8[ch][i]
    int ch = t >> 6, i = t & 63;
    int p = ((i >> 3) << 5) + ((i & 7) << 1);
    float a = ebv[ch];
#pragma unroll 8
    for (int k = 0; k < 64; ++k)
      a += effs[ch][k] * x3[((size_t)(b * 64 + k)) * 256 + p];
    s8v[ch][i] = fmaxf(a, 0.f);
  }
  __syncthreads();
  if (t < 64) {  // 2x2 mean pool
    int ch = t >> 4, q = t & 15;
    int py = q >> 2, qx = q & 3;
    int i0 = (py * 2) * 8 + qx * 2;
    scv[t] = 0.25f * (s8v[ch][i0] + s8v[ch][i0 + 1] + s8v[ch][i0 + 8] +
                      s8v[ch][i0 + 9]);
  }
  __syncthreads();

  if (t < 64) {  // FC1 (overlaps splat)
    float a = fb1[t];
#pragma unroll 8
    for (int k = 0; k < 64; ++k) a += fw1[t * 64 + k] * scv[k];
    h1v[t] = fmaxf(a, 0.f);
  }
  if (t < 128) {  // splat (no relu): og=t>>1, u=t&1
    int u = t & 1, og = t >> 1;
    float acc = spb[og] + val[b];
#pragma unroll 4
    for (int k = 0; k < 64; k += 4) {
      float4 wv = *(const float4*)&spw[og * 64 + k];
      acc += wv.x * A[k][u] + wv.y * A[k + 1][u] + wv.z * A[k + 2][u] +
             wv.w * A[k + 3][u];
    }
    Bf[og][u] = acc;
  }
  __syncthreads();
  if (t < 64) {  // FC2 (overlaps loc1)
    float a = fb2[t];
#pragma unroll 8
    for (int k = 0; k < 64; ++k) a += fw2[t * 64 + k] * h1v[k];
    f2v[t] = fmaxf(a, 0.f);
  }
  {  // loc1: 64->128, all threads
    int u = t & 1, og = t >> 1;
    float acc = lb1[og];
#pragma unroll 4
    for (int k = 0; k < 64; k += 4) {
      float4 wv = *(const float4*)&lw1[og * 64 + k];
      acc += wv.x * Bf[k][u] + wv.y * Bf[k + 1][u] + wv.z * Bf[k + 2][u] +
             wv.w * Bf[k + 3][u];
    }
    A[og][u] = fmaxf(acc, 0.f);
  }
  __syncthreads();
  {  // loc2: 128->128, all threads
    int u = t & 1, og = t >> 1;
    float acc = lb2[og];
#pragma unroll 4
    for (int k = 0; k < 128; k += 4) {
      float4 wv = *(const float4*)&lw2[og * 128 + k];
      acc += wv.x * A[k][u] + wv.y * A[k + 1][u] + wv.z * A[k + 2][u] +
             wv.w * A[k + 3][u];
    }
    Bf[og][u] = fmaxf(acc, 0.f);
  }
  __syncthreads();
  if (t < 128) {  // loc3: 128->64
    int u = t & 1, og = t >> 1;
    float acc = lb3[og];
#pragma unroll 4
    for (int k = 0; k < 128; k += 4) {
      float4 wv = *(const float4*)&lw3[og * 128 + k];
      acc += wv.x * Bf[k][u] + wv.y * Bf[k + 1][u] + wv.z * Bf[k + 2][u] +
             wv.w * Bf[k + 3][u];
    }
    A[og][u] = fmaxf(acc, 0.f);
  }
  __syncthreads();
  if (t < 192) {  // coeff: 96 ch x 2 pos; fused = relu(loc3 + f2v)
    int u = t & 1, og = t >> 1;
    float acc = gb[og];
#pragma unroll 4
    for (int k = 0; k < 64; k += 4) {
      float4 cc4 = *(const float4*)&f2v[k];
      float q0 = fmaxf(A[k][u] + cc4.x, 0.f);
      float q1 = fmaxf(A[k + 1][u] + cc4.y, 0.f);
      float q2 = fmaxf(A[k + 2][u] + cc4.z, 0.f);
      float q3 = fmaxf(A[k + 3][u] + cc4.w, 0.f);
      float4 wv = *(const float4*)&gw[og * 64 + k];
      acc += wv.x * q0 + wv.y * q1 + wv.z * q2 + wv.w * q3;
    }
    int l = og / 12, cc = og - l * 12;
    gridt[(size_t)(((b * 8 + l) << 8) + p0 + u) * 12 + cc] = acc;
  }
}

// ---------------- guide + bilateral slice + affine apply (fused, LDS grid) ----
// ZST=204: word-offset 204*zi+12*xi -> bank group 12*(zi+xi) mod 32, 8 distinct
// groups over zi mod 8 (ZST=200 collided zi with zi+4 -> 4-way conflicts).
#define ZST 204
__global__ __launch_bounds__(256, 6) void slice_k(
    const float* __restrict__ img, const float* __restrict__ gridt,
    const float* __restrict__ ccm_w, const float* __restrict__ ccm_b,
    const float* __restrict__ shifts, const float* __restrict__ slopes,
    const float* __restrict__ prw, const float* __restrict__ prb,
    float* __restrict__ out) {
  int blk = blockIdx.x;          // BATCH*1024
  int b = blk >> 10;
  int h = blk & 1023;
  int t = threadIdx.x;

  __shared__ float sg[8 * ZST];      // 6528 B
  __shared__ float2 lut[3][16];      // CS, CB

  float cy = (h + 0.5f) * 0.015625f - 0.5f;
  float y0f = floorf(cy);
  float wy = cy - y0f;
  int y0 = (int)y0f;
  int yi0 = min(max(y0, 0), 15), yi1 = min(max(y0 + 1, 0), 15);

  if (t < 48) {
    int c = t >> 4, k = t & 15;
    float cs = 0.f, cbv = 0.f;
    for (int i = 0; i <= k; ++i) {
      float s = slopes[c * 16 + i];
      cs += s;
      cbv += s * shifts[c * 16 + i];
    }
    lut[c][k] = make_float2(cs, cbv);
  }

  for (int i = t; i < 384; i += 256) {
    int z = i / 48;
    int e = i - z * 48;
    const float4* s0 =
        (const float4*)(gridt + (size_t)(((b * 8 + z) << 8) + (yi0 << 4)) * 12);
    const float4* s1 =
        (const float4*)(gridt + (size_t)(((b * 8 + z) << 8) + (yi1 << 4)) * 12);
    float4 a = s0[e], c = s1[e];
    float4 v = make_float4(a.x + wy * (c.x - a.x), a.y + wy * (c.y - a.y),
                           a.z + wy * (c.z - a.z), a.w + wy * (c.w - a.w));
    *((float4*)(sg + z * ZST) + e) = v;
  }
  __syncthreads();

  int pp = (h << 10) + (t << 2);
  const float* ib = img + (size_t)b * 3 * HH * WW;
  float4 R4 = *(const float4*)(ib + pp);
  float4 G4 = *(const float4*)(ib + HH * WW + pp);
  float4 B4 = *(const float4*)(ib + 2 * HH * WW + pp);
  float r_[4] = {R4.x, R4.y, R4.z, R4.w};
  float g_[4] = {G4.x, G4.y, G4.z, G4.w};
  float b_[4] = {B4.x, B4.y, B4.z, B4.w};

  float m0 = ccm_w[0], m1 = ccm_w[1], m2 = ccm_w[2];
  float m3 = ccm_w[3], m4 = ccm_w[4], m5 = ccm_w[5];
  float m6 = ccm_w[6], m7 = ccm_w[7], m8 = ccm_w[8];
  float c0 = ccm_b[0], c1 = ccm_b[1], c2 = ccm_b[2];
  float p0 = prw[0], p1 = prw[1], p2 = prw[2], pb = prb[0];

  float base0 = shifts[0], base1 = shifts[16], base2 = shifts[32];
  float inv0 = 1.0f / (shifts[1] - base0);
  float inv1 = 1.0f / (shifts[17] - base1);
  float inv2 = 1.0f / (shifts[33] - base2);

  float ro[4], go[4], bo[4];
#pragma unroll
  for (int j = 0; j < 4; ++j) {
    float r = r_[j], g = g_[j], bl = b_[j];
    float v0 = c0 + m0 * r + m1 * g + m2 * bl;
    float v1 = c1 + m3 * r + m4 * g + m5 * bl;
    float v2 = c2 + m6 * r + m7 * g + m8 * bl;

    float tv0 = fmaxf(v0, base0);
    float tv1 = fmaxf(v1, base1);
    float tv2 = fmaxf(v2, base2);
    int j0 = min((int)((tv0 - base0) * inv0), 15);
    int j1 = min((int)((tv1 - base1) * inv1), 15);
    int j2 = min((int)((tv2 - base2) * inv2), 15);
    float2 e0 = lut[0][j0];
    float2 e1 = lut[1][j1];
    float2 e2 = lut[2][j2];
    float f0 = e0.x * tv0 - e0.y;
    float f1 = e1.x * tv1 - e1.y;
    float f2 = e2.x * tv2 - e2.y;

    float gg = pb + p0 * f0 + p1 * f1 + p2 * f2;
    float guide = fminf(fmaxf(gg, 0.f), 1.f);

    int w = (t << 2) + j;
    float cx = (w + 0.5f) * 0.015625f - 0.5f;
    float x0f = floorf(cx);
    float wx = cx - x0f;
    int x0i = (int)x0f;
    int xi0 = min(max(x0i, 0), 15), xi1 = min(max(x0i + 1, 0), 15);

    float cz = guide * 8.0f - 0.5f;
    float z0f = floorf(cz);
    float wz = cz - z0f;
    int z0i = (int)z0f;
    int zi0 = min(max(z0i, 0), 7), zi1 = min(max(z0i + 1, 0), 7);

    int oz0 = zi0 * ZST, oz1 = zi1 * ZST;
    int ox0 = xi0 * 12, ox1 = xi1 * 12;
    float wz1 = wz, wz0 = 1.f - wz;
    float wx1 = wx, wx0 = 1.f - wx;

    float rr = 0.f, gg2 = 0.f, bb2 = 0.f;
#pragma unroll
    for (int dz = 0; dz < 2; ++dz) {
      int oz = dz ? oz1 : oz0;
      float wzz = dz ? wz1 : wz0;
#pragma unroll
      for (int dx = 0; dx < 2; ++dx) {
        int ox = dx ? ox1 : ox0;
        float wgt = wzz * (dx ? wx1 : wx0);
        const float* gp = sg + oz + ox;
        float4 a0 = *(const float4*)gp;
        float4 a1 = *(const float4*)(gp + 4);
        float4 a2 = *(const float4*)(gp + 8);
        rr  += wgt * (a0.x * r + a0.y * g + a0.z * bl + a0.w);
        gg2 += wgt * (a1.x * r + a1.y * g + a1.z * bl + a1.w);
        bb2 += wgt * (a2.x * r + a2.y * g + a2.z * bl + a2.w);
      }
    }
    ro[j] = rr;
    go[j] = gg2;
    bo[j] = bb2;
  }
  float* ob = out + (size_t)b * 3 * HH * WW;
  *(float4*)(ob + pp) = make_float4(ro[0], ro[1], ro[2], ro[3]);
  *(float4*)(ob + HH * WW + pp) = make_float4(go[0], go[1], go[2], go[3]);
  *(float4*)(ob + 2 * HH * WW + pp) = make_float4(bo[0], bo[1], bo[2], bo[3]);
}

extern "C" void kernel_launch(void* const* d_in, const int* in_sizes, int n_in,
                              void* d_out, int out_size, void* d_ws, size_t ws_size,
                              hipStream_t stream) {
  const float* image = (const float*)d_in[0];
  const float* val   = (const float*)d_in[1];
  const float* sw0 = (const float*)d_in[2];  const float* sb0 = (const float*)d_in[3];
  const float* sw1 = (const float*)d_in[4];  const float* sb1 = (const float*)d_in[5];
  const float* sw2 = (const float*)d_in[6];  const float* sb2 = (const float*)d_in[7];
  const float* sw3 = (const float*)d_in[8];  const float* sb3 = (const float*)d_in[9];
  const float* spw = (const float*)d_in[10]; const float* spb = (const float*)d_in[11];
  const float* lw1 = (const float*)d_in[12]; const float* lb1 = (const float*)d_in[13];
  const float* lw2 = (const float*)d_in[14]; const float* lb2 = (const float*)d_in[15];
  const float* lw3 = (const float*)d_in[16]; const float* lb3 = (const float*)d_in[17];
  const float* cw  = (const float*)d_in[18]; const float* cb  = (const float*)d_in[19];
  const float* fw1 = (const float*)d_in[20]; const float* fb1 = (const float*)d_in[21];
  const float* fw2 = (const float*)d_in[22]; const float* fb2 = (const float*)d_in[23];
  const float* gw  = (const float*)d_in[24]; const float* gb  = (const float*)d_in[25];
  const float* ccm_w = (const float*)d_in[26]; const float* ccm_b = (const float*)d_in[27];
  const float* shifts = (const float*)d_in[28]; const float* slopes = (const float*)d_in[29];
  const float* prw = (const float*)d_in[30]; const float* prb = (const float*)d_in[31];
  float* out = (float*)d_out;

  float* ws    = (float*)d_ws;
  float* x0    = ws;                  // (unused; layout kept)
  float* x1    = x0 + 524288;         // 262144
  float* x2    = x1 + 262144;         // (unused after conv23 fusion)
  float* x3    = x2 + 131072;         // 65536
  float* gridt = x3 + 65536 + 256;    // 98304

  ds01_k<<<1024, 256, 0, stream>>>(image, sw0, sb0, sw1, sb1, x1);
  conv23_k<<<256, 256, 0, stream>>>(x1, sw2, sb2, sw3, sb3, x3);
  mlp_k<<<512, 256, 0, stream>>>(x3, spw, spb, val, lw1, lb1, lw2, lb2, lw3, lb3,
                                 cw, cb, fw1, fb1, fw2, fb2, gw, gb, gridt);
  slice_k<<<4096, 256, 0, stream>>>(image, gridt, ccm_w, ccm_b, shifts, slopes,
                                    prw, prb, out);
}

// Round 10
// 221.860 us; speedup vs baseline: 1.0269x; 1.0269x over previous
//
#include <hip/hip_runtime.h>

#define BATCH 4
#define HH 1024
#define WW 1024

// ------- fused downsample(1024->256) + conv0 (3->8,s2) + conv1 (8->16,s2) ----
// 1024 blocks (4/CU). Each block: 4x4 x1-tile.
__global__ __launch_bounds__(256) void ds01_k(const float* __restrict__ img,
                                              const float* __restrict__ w0,
                                              const float* __restrict__ b0,
                                              const float* __restrict__ w1,
                                              const float* __restrict__ b1,
                                              float* __restrict__ out) {
  int blk = blockIdx.x;            // b*256 + ty*16 + tx
  int tx = blk & 15;
  int ty = (blk >> 4) & 15;
  int b = blk >> 8;
  int t = threadIdx.x;

  __shared__ float low[3][19][21];   // 4.8 KB
  __shared__ float x0s[8][9][12];    // 3.5 KB

  int Y0 = ty << 2, X0 = tx << 2;           // x1 tile origin (64x64 space)
  int gy0 = 2 * Y0 - 1, gx0 = 2 * X0 - 1;   // x0 support origin (9x9)
  int ly0 = 2 * gy0 - 1, lx0 = 2 * gx0 - 1; // low support origin (19x19)

  for (int i = t; i < 3 * 19 * 19; i += 256) {
    int c = i / 361;
    int rem = i - c * 361;
    int ly = rem / 19;
    int lx = rem - ly * 19;
    int gy = ly0 + ly, gx = lx0 + lx;        // in [-3, 255]
    float v = 0.f;
    if (gy >= 0 && gx >= 0) {
      const float* p = img + (size_t)(b * 3 + c) * HH * WW + (4 * gy + 1) * WW + 4 * gx;
      float4 u0 = *(const float4*)p;
      float4 u1 = *(const float4*)(p + WW);
      v = 0.25f * (u0.y + u0.z + u1.y + u1.z);
    }
    low[c][ly][lx] = v;
  }
  __syncthreads();

  for (int i = t; i < 8 * 81; i += 256) {
    int ch = i / 81;
    int pos = i - ch * 81;
    int py = pos / 9, px = pos - py * 9;
    int gy = gy0 + py, gx = gx0 + px;
    float v = 0.f;
    if (gy >= 0 && gx >= 0) {
      float a = b0[ch];
#pragma unroll
      for (int ci = 0; ci < 3; ++ci)
#pragma unroll
        for (int ky = 0; ky < 3; ++ky)
#pragma unroll
          for (int kx = 0; kx < 3; ++kx)
            a += low[ci][2 * py + ky][2 * px + kx] *
                 w0[ch * 27 + ci * 9 + ky * 3 + kx];
      v = fmaxf(a, 0.f);
    }
    x0s[ch][py][px] = v;
  }
  __syncthreads();

  {
    int oc = t >> 4;
    int pos = t & 15;
    int y = pos >> 2, x = pos & 3;
    float a = b1[oc];
#pragma unroll
    for (int ci = 0; ci < 8; ++ci)
#pragma unroll
      for (int ky = 0; ky < 3; ++ky)
#pragma unroll
        for (int kx = 0; kx < 3; ++kx)
          a += x0s[ci][2 * y + ky][2 * x + kx] *
               w1[(oc * 8 + ci) * 9 + ky * 3 + kx];
    out[(size_t)(b * 16 + oc) * 64 * 64 + (Y0 + y) * 64 + X0 + x] =
        fmaxf(a, 0.f);
  }
}

// ---------------- LDS-tiled 3x3 s2 conv, PxP output tile ---------------------
// Grid MUST be BATCH * NT * NT where NT = (HI/2)/P.
template <int CI, int CO, int HI, int P>
__global__ __launch_bounds__(256) void conv_tile_k(const float* __restrict__ in,
                                                   const float* __restrict__ wgt,
                                                   const float* __restrict__ bias,
                                                   float* __restrict__ out) {
  const int HO = HI / 2;
  const int NT = HO / P;
  const int HALO = 2 * P + 1;
  const int RS = 2 * P + 4;       // padded row stride
  constexpr int NO = (CO * P * P) / 256;
  int blk = blockIdx.x;
  int tx = blk % NT;
  int ty = (blk / NT) % NT;
  int b = blk / (NT * NT);
  int t = threadIdx.x;

  __shared__ float s[CI][HALO][RS];

  int Y0 = ty * P, X0 = tx * P;
  int gy0 = 2 * Y0 - 1, gx0 = 2 * X0 - 1;

  for (int i = t; i < CI * HALO * HALO; i += 256) {
    int c = i / (HALO * HALO);
    int rem = i - c * (HALO * HALO);
    int ly = rem / HALO;
    int lx = rem - ly * HALO;
    int gy = gy0 + ly, gx = gx0 + lx;
    float v = 0.f;
    if (gy >= 0 && gy < HI && gx >= 0 && gx < HI)
      v = in[((size_t)(b * CI + c) * HI + gy) * HI + gx];
    s[c][ly][lx] = v;
  }
  __syncthreads();

  int px = t % (P * P);
  int og = t / (P * P);
  int x = px % P, y = px / P;
  float acc[NO];
#pragma unroll
  for (int j = 0; j < NO; ++j) acc[j] = bias[og * NO + j];
  for (int ci = 0; ci < CI; ++ci) {
#pragma unroll
    for (int ky = 0; ky < 3; ++ky) {
#pragma unroll
      for (int kx = 0; kx < 3; ++kx) {
        float v = s[ci][2 * y + ky][2 * x + kx];
#pragma unroll
        for (int j = 0; j < NO; ++j)
          acc[j] += wgt[((og * NO + j) * CI + ci) * 9 + ky * 3 + kx] * v;
      }
    }
  }
#pragma unroll
  for (int j = 0; j < NO; ++j)
    out[(size_t)(b * CO + og * NO + j) * HO * HO + (Y0 + y) * HO + X0 + x] =
        fmaxf(acc[j], 0.f);
}

// ---------------- fused pointwise chain, 4 positions/block (256 blocks) ------
template <int CI, int RELU>
__device__ __forceinline__ void pw4_c64(const float (*__restrict__ X)[4],
                                        float (*__restrict__ Y)[4],
                                        const float* __restrict__ w,
                                        const float* __restrict__ bias,
                                        float badd, int t) {
  int u = t & 3, og = t >> 2;  // og 0..63
  float acc = bias[og] + badd;
#pragma unroll 4
  for (int k = 0; k < CI; k += 4) {
    float4 wv = *(const float4*)&w[og * CI + k];
    acc += wv.x * X[k][u] + wv.y * X[k + 1][u] + wv.z * X[k + 2][u] +
           wv.w * X[k + 3][u];
  }
  if (RELU) acc = fmaxf(acc, 0.f);
  Y[og][u] = acc;
}

template <int CI, int RELU>
__device__ __forceinline__ void pw4_c128(const float (*__restrict__ X)[4],
                                         float (*__restrict__ Y)[4],
                                         const float* __restrict__ w,
                                         const float* __restrict__ bias,
                                         int t) {
  int u0 = (t & 1) << 1, og = t >> 1;  // og 0..127
  float a0 = bias[og], a1 = a0;
#pragma unroll 4
  for (int k = 0; k < CI; k += 4) {
    float4 wv = *(const float4*)&w[og * CI + k];
    float2 x0 = *(const float2*)&X[k][u0];
    float2 x1 = *(const float2*)&X[k + 1][u0];
    float2 x2 = *(const float2*)&X[k + 2][u0];
    float2 x3v = *(const float2*)&X[k + 3][u0];
    a0 += wv.x * x0.x + wv.y * x1.x + wv.z * x2.x + wv.w * x3v.x;
    a1 += wv.x * x0.y + wv.y * x1.y + wv.z * x2.y + wv.w * x3v.y;
  }
  if (RELU) { a0 = fmaxf(a0, 0.f); a1 = fmaxf(a1, 0.f); }
  Y[og][u0] = a0;
  Y[og][u0 + 1] = a1;
}

__global__ __launch_bounds__(256) void mlp_k(
    const float* __restrict__ x3, const float* __restrict__ spw,
    const float* __restrict__ spb, const float* __restrict__ val,
    const float* __restrict__ lw1, const float* __restrict__ lb1,
    const float* __restrict__ lw2, const float* __restrict__ lb2,
    const float* __restrict__ lw3, const float* __restrict__ lb3,
    const float* __restrict__ cw, const float* __restrict__ cb,
    const float* __restrict__ fw1, const float* __restrict__ fb1,
    const float* __restrict__ fw2, const float* __restrict__ fb2,
    const float* __restrict__ gw, const float* __restrict__ gb,
    float* __restrict__ gridt) {
  int blk = blockIdx.x;  // b*64 + g
  int b = blk >> 6;
  int p0 = (blk & 63) << 2;
  int t = threadIdx.x;

  __shared__ __align__(16) float A[128][4];
  __shared__ __align__(16) float Bf[128][4];
  __shared__ float effs[4][64];
  __shared__ float ebv[4];
  __shared__ float s8v[4][64];
  __shared__ float scv[64], h1v[64], f2v[64];

  A[t >> 2][t & 3] = x3[((size_t)(b * 64 + (t >> 2))) * 256 + p0 + (t & 3)];
  {  // eff[ch][k] = sum_o cw[ch][o]*spw[o][k]
    int ch = t >> 6, k = t & 63;
    float a = 0.f;
#pragma unroll 8
    for (int o = 0; o < 64; ++o) a += cw[ch * 64 + o] * spw[o * 64 + k];
    effs[ch][k] = a;
    if (k == 0) {
      float a2 = 0.f;
      float vb = val[b];
#pragma unroll 8
      for (int o = 0; o < 64; ++o) a2 += cw[ch * 64 + o] * (spb[o] + vb);
      ebv[ch] = cb[ch] + a2;
    }
  }
  __syncthreads();
  {  // s8[ch][i]
    int ch = t >> 6, i = t & 63;
    int p = ((i >> 3) << 5) + ((i & 7) << 1);
    float a = ebv[ch];
#pragma unroll 8
    for (int k = 0; k < 64; ++k)
      a += effs[ch][k] * x3[((size_t)(b * 64 + k)) * 256 + p];
    s8v[ch][i] = fmaxf(a, 0.f);
  }
  __syncthreads();
  if (t < 64) {  // 2x2 mean pool
    int ch = t >> 4, q = t & 15;
    int py = q >> 2, qx = q & 3;
    int i0 = (py * 2) * 8 + qx * 2;
    scv[t] = 0.25f * (s8v[ch][i0] + s8v[ch][i0 + 1] + s8v[ch][i0 + 8] +
                      s8v[ch][i0 + 9]);
  }
  __syncthreads();

  if (t < 64) {  // FC1 (overlaps splat)
    float a = fb1[t];
#pragma unroll 8
    for (int k = 0; k < 64; ++k) a += fw1[t * 64 + k] * scv[k];
    h1v[t] = fmaxf(a, 0.f);
  }
  {  // splat (no relu)
    int u = t & 3, og = t >> 2;
    float acc = spb[og] + val[b];
#pragma unroll 4
    for (int k = 0; k < 64; k += 4) {
      float4 wv = *(const float4*)&spw[og * 64 + k];
      acc += wv.x * A[k][u] + wv.y * A[k + 1][u] + wv.z * A[k + 2][u] +
             wv.w * A[k + 3][u];
    }
    Bf[og][u] = acc;
  }
  __syncthreads();
  if (t < 64) {  // FC2 (overlaps loc1)
    float a = fb2[t];
#pragma unroll 8
    for (int k = 0; k < 64; ++k) a += fw2[t * 64 + k] * h1v[k];
    f2v[t] = fmaxf(a, 0.f);
  }
  pw4_c128<64, 1>(Bf, A, lw1, lb1, t);          // loc1
  __syncthreads();
  pw4_c128<128, 1>(A, Bf, lw2, lb2, t);         // loc2
  __syncthreads();
  pw4_c64<128, 1>(Bf, A, lw3, lb3, 0.f, t);     // loc3
  __syncthreads();

  {  // coeff: 96 channels x 4 positions; fused = relu(loc3 + f2v)
    int u0 = (t & 1) << 1, og = t >> 1;
    if (og < 96) {
      float a0 = gb[og], a1 = a0;
#pragma unroll 4
      for (int k = 0; k < 64; k += 4) {
        float4 cc4 = *(const float4*)&f2v[k];
        float2 q0 = *(const float2*)&A[k][u0];
        float2 q1 = *(const float2*)&A[k + 1][u0];
        float2 q2 = *(const float2*)&A[k + 2][u0];
        float2 q3 = *(const float2*)&A[k + 3][u0];
        q0.x = fmaxf(q0.x + cc4.x, 0.f); q0.y = fmaxf(q0.y + cc4.x, 0.f);
        q1.x = fmaxf(q1.x + cc4.y, 0.f); q1.y = fmaxf(q1.y + cc4.y, 0.f);
        q2.x = fmaxf(q2.x + cc4.z, 0.f); q2.y = fmaxf(q2.y + cc4.z, 0.f);
        q3.x = fmaxf(q3.x + cc4.w, 0.f); q3.y = fmaxf(q3.y + cc4.w, 0.f);
        float4 wv = *(const float4*)&gw[og * 64 + k];
        a0 += wv.x * q0.x + wv.y * q1.x + wv.z * q2.x + wv.w * q3.x;
        a1 += wv.x * q0.y + wv.y * q1.y + wv.z * q2.y + wv.w * q3.y;
      }
      int l = og / 12, cc = og - l * 12;
      gridt[(size_t)(((b * 8 + l) << 8) + p0 + u0) * 12 + cc] = a0;
      gridt[(size_t)(((b * 8 + l) << 8) + p0 + u0 + 1) * 12 + cc] = a1;
    }
  }
}

// ---------------- guide + bilateral slice + affine apply (fused, LDS grid) ----
// ZST=204 (single isolated change vs R6's 223.1 baseline): word-offset
// 204*zi+12*xi -> 204%32=12, so the 8 z-slabs map to 8 distinct bank groups;
// ZST=200 (%32=8) collided zi with zi+4 -> data-dependent ~4-way conflicts
// on the corner-gather ds_read_b128 stream.
#define ZST 204
__global__ __launch_bounds__(256, 6) void slice_k(
    const float* __restrict__ img, const float* __restrict__ gridt,
    const float* __restrict__ ccm_w, const float* __restrict__ ccm_b,
    const float* __restrict__ shifts, const float* __restrict__ slopes,
    const float* __restrict__ prw, const float* __restrict__ prb,
    float* __restrict__ out) {
  int blk = blockIdx.x;          // BATCH*1024
  int b = blk >> 10;
  int h = blk & 1023;
  int t = threadIdx.x;

  __shared__ float sg[8 * ZST];      // 6528 B
  __shared__ float2 lut[3][16];      // CS, CB

  float cy = (h + 0.5f) * 0.015625f - 0.5f;
  float y0f = floorf(cy);
  float wy = cy - y0f;
  int y0 = (int)y0f;
  int yi0 = min(max(y0, 0), 15), yi1 = min(max(y0 + 1, 0), 15);

  if (t < 48) {
    int c = t >> 4, k = t & 15;
    float cs = 0.f, cbv = 0.f;
    for (int i = 0; i <= k; ++i) {
      float s = slopes[c * 16 + i];
      cs += s;
      cbv += s * shifts[c * 16 + i];
    }
    lut[c][k] = make_float2(cs, cbv);
  }

  for (int i = t; i < 384; i += 256) {
    int z = i / 48;
    int e = i - z * 48;
    const float4* s0 =
        (const float4*)(gridt + (size_t)(((b * 8 + z) << 8) + (yi0 << 4)) * 12);
    const float4* s1 =
        (const float4*)(gridt + (size_t)(((b * 8 + z) << 8) + (yi1 << 4)) * 12);
    float4 a = s0[e], c = s1[e];
    float4 v = make_float4(a.x + wy * (c.x - a.x), a.y + wy * (c.y - a.y),
                           a.z + wy * (c.z - a.z), a.w + wy * (c.w - a.w));
    *((float4*)(sg + z * ZST) + e) = v;
  }
  __syncthreads();

  int pp = (h << 10) + (t << 2);
  const float* ib = img + (size_t)b * 3 * HH * WW;
  float4 R4 = *(const float4*)(ib + pp);
  float4 G4 = *(const float4*)(ib + HH * WW + pp);
  float4 B4 = *(const float4*)(ib + 2 * HH * WW + pp);
  float r_[4] = {R4.x, R4.y, R4.z, R4.w};
  float g_[4] = {G4.x, G4.y, G4.z, G4.w};
  float b_[4] = {B4.x, B4.y, B4.z, B4.w};

  float m0 = ccm_w[0], m1 = ccm_w[1], m2 = ccm_w[2];
  float m3 = ccm_w[3], m4 = ccm_w[4], m5 = ccm_w[5];
  float m6 = ccm_w[6], m7 = ccm_w[7], m8 = ccm_w[8];
  float c0 = ccm_b[0], c1 = ccm_b[1], c2 = ccm_b[2];
  float p0 = prw[0], p1 = prw[1], p2 = prw[2], pb = prb[0];

  float base0 = shifts[0], base1 = shifts[16], base2 = shifts[32];
  float inv0 = 1.0f / (shifts[1] - base0);
  float inv1 = 1.0f / (shifts[17] - base1);
  float inv2 = 1.0f / (shifts[33] - base2);

  float ro[4], go[4], bo[4];
#pragma unroll
  for (int j = 0; j < 4; ++j) {
    float r = r_[j], g = g_[j], bl = b_[j];
    float v0 = c0 + m0 * r + m1 * g + m2 * bl;
    float v1 = c1 + m3 * r + m4 * g + m5 * bl;
    float v2 = c2 + m6 * r + m7 * g + m8 * bl;

    float tv0 = fmaxf(v0, base0);
    float tv1 = fmaxf(v1, base1);
    float tv2 = fmaxf(v2, base2);
    int j0 = min((int)((tv0 - base0) * inv0), 15);
    int j1 = min((int)((tv1 - base1) * inv1), 15);
    int j2 = min((int)((tv2 - base2) * inv2), 15);
    float2 e0 = lut[0][j0];
    float2 e1 = lut[1][j1];
    float2 e2 = lut[2][j2];
    float f0 = e0.x * tv0 - e0.y;
    float f1 = e1.x * tv1 - e1.y;
    float f2 = e2.x * tv2 - e2.y;

    float gg = pb + p0 * f0 + p1 * f1 + p2 * f2;
    float guide = fminf(fmaxf(gg, 0.f), 1.f);

    int w = (t << 2) + j;
    float cx = (w + 0.5f) * 0.015625f - 0.5f;
    float x0f = floorf(cx);
    float wx = cx - x0f;
    int x0i = (int)x0f;
    int xi0 = min(max(x0i, 0), 15), xi1 = min(max(x0i + 1, 0), 15);

    float cz = guide * 8.0f - 0.5f;
    float z0f = floorf(cz);
    float wz = cz - z0f;
    int z0i = (int)z0f;
    int zi0 = min(max(z0i, 0), 7), zi1 = min(max(z0i + 1, 0), 7);

    int oz0 = zi0 * ZST, oz1 = zi1 * ZST;
    int ox0 = xi0 * 12, ox1 = xi1 * 12;
    float wz1 = wz, wz0 = 1.f - wz;
    float wx1 = wx, wx0 = 1.f - wx;

    float rr = 0.f, gg2 = 0.f, bb2 = 0.f;
#pragma unroll
    for (int dz = 0; dz < 2; ++dz) {
      int oz = dz ? oz1 : oz0;
      float wzz = dz ? wz1 : wz0;
#pragma unroll
      for (int dx = 0; dx < 2; ++dx) {
        int ox = dx ? ox1 : ox0;
        float wgt = wzz * (dx ? wx1 : wx0);
        const float* gp = sg + oz + ox;
        float4 a0 = *(const float4*)gp;
        float4 a1 = *(const float4*)(gp + 4);
        float4 a2 = *(const float4*)(gp + 8);
        rr  += wgt * (a0.x * r + a0.y * g + a0.z * bl + a0.w);
        gg2 += wgt * (a1.x * r + a1.y * g + a1.z * bl + a1.w);
        bb2 += wgt * (a2.x * r + a2.y * g + a2.z * bl + a2.w);
      }
    }
    ro[j] = rr;
    go[j] = gg2;
    bo[j] = bb2;
  }
  float* ob = out + (size_t)b * 3 * HH * WW;
  *(float4*)(ob + pp) = make_float4(ro[0], ro[1], ro[2], ro[3]);
  *(float4*)(ob + HH * WW + pp) = make_float4(go[0], go[1], go[2], go[3]);
  *(float4*)(ob + 2 * HH * WW + pp) = make_float4(bo[0], bo[1], bo[2], bo[3]);
}

extern "C" void kernel_launch(void* const* d_in, const int* in_sizes, int n_in,
                              void* d_out, int out_size, void* d_ws, size_t ws_size,
                              hipStream_t stream) {
  const float* image = (const float*)d_in[0];
  const float* val   = (const float*)d_in[1];
  const float* sw0 = (const float*)d_in[2];  const float* sb0 = (const float*)d_in[3];
  const float* sw1 = (const float*)d_in[4];  const float* sb1 = (const float*)d_in[5];
  const float* sw2 = (const float*)d_in[6];  const float* sb2 = (const float*)d_in[7];
  const float* sw3 = (const float*)d_in[8];  const float* sb3 = (const float*)d_in[9];
  const float* spw = (const float*)d_in[10]; const float* spb = (const float*)d_in[11];
  const float* lw1 = (const float*)d_in[12]; const float* lb1 = (const float*)d_in[13];
  const float* lw2 = (const float*)d_in[14]; const float* lb2 = (const float*)d_in[15];
  const float* lw3 = (const float*)d_in[16]; const float* lb3 = (const float*)d_in[17];
  const float* cw  = (const float*)d_in[18]; const float* cb  = (const float*)d_in[19];
  const float* fw1 = (const float*)d_in[20]; const float* fb1 = (const float*)d_in[21];
  const float* fw2 = (const float*)d_in[22]; const float* fb2 = (const float*)d_in[23];
  const float* gw  = (const float*)d_in[24]; const float* gb  = (const float*)d_in[25];
  const float* ccm_w = (const float*)d_in[26]; const float* ccm_b = (const float*)d_in[27];
  const float* shifts = (const float*)d_in[28]; const float* slopes = (const float*)d_in[29];
  const float* prw = (const float*)d_in[30]; const float* prb = (const float*)d_in[31];
  float* out = (float*)d_out;

  float* ws    = (float*)d_ws;
  float* x0    = ws;                  // (unused; layout kept)
  float* x1    = x0 + 524288;         // 262144
  float* x2    = x1 + 262144;         // 131072
  float* x3    = x2 + 131072;         // 65536
  float* gridt = x3 + 65536 + 256;    // 98304

  ds01_k<<<1024, 256, 0, stream>>>(image, sw0, sb0, sw1, sb1, x1);
  conv_tile_k<16, 32, 64, 4><<<256, 256, 0, stream>>>(x1, sw2, sb2, x2);
  conv_tile_k<32, 64, 32, 2><<<256, 256, 0, stream>>>(x2, sw3, sb3, x3);
  mlp_k<<<256, 256, 0, stream>>>(x3, spw, spb, val, lw1, lb1, lw2, lb2, lw3, lb3,
                                 cw, cb, fw1, fb1, fw2, fb2, gw, gb, gridt);
  slice_k<<<4096, 256, 0, stream>>>(image, gridt, ccm_w, ccm_b, shifts, slopes,
                                    prw, prb, out);
}